// Round 1
// 2123.875 us; speedup vs baseline: 1.0844x; 1.0844x over previous
//
#include <hip/hip_runtime.h>
#include <stdint.h>

// ---------------------------------------------------------------------------
// HeteroRGCNLayer on MI355X. Inputs/outputs float32; MFMA compute in bf16.
// D=256, N_TOK=50000, N_SRL=20000, N_ENT=10000, T=50000
// E_TS=300000, E_EE=150000, E_ST=300000, E_ET=150000
// R4: coalesced 3-pass cumsum; GEMM stages A once per block and loops n-tiles
// (A HBM refetch 12x -> <=3x); EE edge GEMM grid right-sized (covering dst =>
// exactly 15 edges/ent, 37500 per 2500-dst chunk).
// R5: cumsum_p2 parallelized (was 188us single-block serial scan @0.05%
// occupancy -> 256 blocks, one per dim, shuffle+LDS block scan; ~5us).
// ---------------------------------------------------------------------------

typedef unsigned short u16;
typedef __bf16 bf16_t;
typedef bf16_t bf16x8 __attribute__((ext_vector_type(8)));
typedef float f32x4 __attribute__((ext_vector_type(4)));

__device__ __forceinline__ float us2f(u16 h) {
  unsigned int u = ((unsigned int)h) << 16;
  return __builtin_bit_cast(float, u);
}
__device__ __forceinline__ u16 f2us(float f) {  // RNE float->bf16
  unsigned int u = __builtin_bit_cast(unsigned int, f);
  u += 0x7FFFu + ((u >> 16) & 1u);
  return (u16)(u >> 16);
}
__device__ __forceinline__ uint4 pack8(float4 a, float4 b) {
  uint4 v;
  v.x = f2us(a.x) | ((unsigned)f2us(a.y) << 16);
  v.y = f2us(a.z) | ((unsigned)f2us(a.w) << 16);
  v.z = f2us(b.x) | ((unsigned)f2us(b.y) << 16);
  v.w = f2us(b.z) | ((unsigned)f2us(b.w) << 16);
  return v;
}
__device__ __forceinline__ float sigm(float x) { return 1.f / (1.f + __expf(-x)); }
__device__ __forceinline__ float tanh_f(float x) {
  x = fminf(fmaxf(x, -15.f), 15.f);
  float e = __expf(2.f * x);
  return (e - 1.f) / (e + 1.f);
}

// ---------------- diagnostics ---------------------------------------------
__global__ void fill_sent(float* out, int n, float v) {
  int i = blockIdx.x * 256 + threadIdx.x;
  if (i < n) out[i] = v;
}

// ---------------- CSR build ------------------------------------------------
__global__ void count_k(const int* __restrict__ dst, int E, int* __restrict__ cnt) {
  int i = blockIdx.x * 256 + threadIdx.x;
  if (i < E) atomicAdd(&cnt[dst[i]], 1);
}

__global__ __launch_bounds__(1024) void scan4_k(int* a0, int n0, int* a1, int n1,
                                                int* a2, int n2, int* a3, int n3) {
  int* a; int n;
  if (blockIdx.x == 0) { a = a0; n = n0; }
  else if (blockIdx.x == 1) { a = a1; n = n1; }
  else if (blockIdx.x == 2) { a = a2; n = n2; }
  else { a = a3; n = n3; }
  __shared__ int swv[16];
  const int t = threadIdx.x, lane = t & 63, wid = t >> 6;
  int carry = 0;
  for (int base = 0; base < n; base += 1024) {
    int r = base + t;
    int v = (r < n) ? a[r] : 0;
    int inc = v;
#pragma unroll
    for (int o = 1; o < 64; o <<= 1) {
      int x = __shfl_up(inc, o, 64);
      if (lane >= o) inc += x;
    }
    if (lane == 63) swv[wid] = inc;
    __syncthreads();
    int wbase = 0, tot = 0;
    for (int w = 0; w < 16; w++) { int s = swv[w]; tot += s; if (w < wid) wbase += s; }
    if (r < n) a[r] = carry + wbase + inc - v;  // exclusive prefix
    carry += tot;
    __syncthreads();
  }
}

__global__ void fill_k(const int* __restrict__ dst, int E, int* __restrict__ off,
                       int* __restrict__ list) {
  int i = blockIdx.x * 256 + threadIdx.x;
  if (i < E) {
    int p = atomicAdd(&off[dst[i]], 1);
    list[p] = i;
  }
}

// ---------------- coalesced 3-pass prefix sum of bert emb ------------------
// chunk = 64 rows per block, 782 blocks; thread t owns dim t (coalesced rows).
__global__ __launch_bounds__(256) void cumsum_p1(const float* __restrict__ emb,
                                                 float* __restrict__ bsum) {
  int b = blockIdx.x, t = threadIdx.x;
  int r0 = b * 64, r1 = min(r0 + 64, 50000);
  float acc = 0.f;
  for (int r = r0; r < r1; r++) acc += emb[(size_t)r * 256 + t];
  bsum[(size_t)b * 256 + t] = acc;
}
// parallel in-place exclusive scan of bsum along the block axis.
// one block per dim d; thread i owns contiguous b-range [4i, 4i+4).
// All traffic L2-resident (800 KB); replaces 188us serial single-block scan.
__global__ __launch_bounds__(256) void cumsum_p2p(float* __restrict__ bsum, int nb) {
  const int d = blockIdx.x;
  const int t = threadIdx.x, lane = t & 63, wid = t >> 6;
  __shared__ float wsum[4];
  float v[4];
  float s = 0.f;
#pragma unroll
  for (int j = 0; j < 4; j++) {
    int b = t * 4 + j;
    v[j] = (b < nb) ? bsum[(size_t)b * 256 + d] : 0.f;
    s += v[j];
  }
  // inclusive wave scan of per-thread sums
  float inc = s;
#pragma unroll
  for (int o = 1; o < 64; o <<= 1) {
    float x = __shfl_up(inc, o, 64);
    if (lane >= o) inc += x;
  }
  if (lane == 63) wsum[wid] = inc;
  __syncthreads();
  float wbase = 0.f;
  for (int w = 0; w < 4; w++) {
    float ws = wsum[w];
    if (w < wid) wbase += ws;
  }
  float excl = wbase + inc - s;  // exclusive prefix across threads
#pragma unroll
  for (int j = 0; j < 4; j++) {
    int b = t * 4 + j;
    if (b < nb) bsum[(size_t)b * 256 + d] = excl;
    excl += v[j];
  }
}
__global__ __launch_bounds__(256) void cumsum_p3(const float* __restrict__ emb,
                                                 const float* __restrict__ bsum,
                                                 float* __restrict__ Pm) {
  int b = blockIdx.x, t = threadIdx.x;
  int r0 = b * 64, r1 = min(r0 + 64, 50000);
  float acc = bsum[(size_t)b * 256 + t];
  if (b == 0) Pm[t] = 0.f;
  for (int r = r0; r < r1; r++) {
    acc += emb[(size_t)r * 256 + t];
    Pm[(size_t)(r + 1) * 256 + t] = acc;
  }
}

// ---------------- derived weights (f32) ------------------------------------
__global__ __launch_bounds__(256) void make_B2(const float* __restrict__ Watt,
                                               const float* __restrict__ Wc,
                                               float* __restrict__ B2) {
  int r = blockIdx.x, k = threadIdx.x;
  float s = 0.f;
  for (int n = 0; n < 256; n++) s += Watt[r * 512 + n] * Wc[n * 256 + k];
  B2[r * 256 + k] = s;
}
__global__ void make_bias2(const float* __restrict__ Watt, const float* __restrict__ bc,
                           float* __restrict__ bias2) {
  int r = threadIdx.x;
  float s = 0.f;
  for (int k = 0; k < 256; k++) s += Watt[r * 512 + k] * bc[k];
  bias2[r] = s;
}
// WW (512x256): rows 0..255 = Wc@Wr2 ; rows 256..511 = B2@Wr2
__global__ __launch_bounds__(256) void make_WW(const float* __restrict__ Wc,
                                               const float* __restrict__ B2,
                                               const float* __restrict__ Wrel,
                                               float* __restrict__ WW) {
  int r = blockIdx.x, k = threadIdx.x;
  const float* X = (r < 256) ? (Wc + (size_t)r * 256) : (B2 + (size_t)(r - 256) * 256);
  float s = 0.f;
  for (int n = 0; n < 256; n++) s += X[n] * Wrel[(size_t)n * 512 + 256 + k];
  WW[(size_t)r * 256 + k] = s;
}

// ---------------------------------------------------------------------------
// N-loop GEMM: C[M x *] = A[M x 256] @ B^T + bias.
// A staged ONCE in LDS (full K, 64 rows), then NT n-tiles of 64 cols looped
// inside the block (B half-K tiles). grid.y selects the NT-tile group.
// AMODE 0: A from memory (ASRC 0 = f32, 1 = bf16). AMODE 2: EE edges — row m
// is edge lst[e_start+m], A[k] = rel/(y-x)*(Pm[y][k]-Pm[x][k]); s2tab residual.
// LDS: As 64x264x2B=33.8K + Bs 64x136x2B=17.4K = 51.2 KB -> 3 blocks/CU.
// ---------------------------------------------------------------------------
template <int AMODE, int ASRC, bool OUTBF>
__global__ __launch_bounds__(256) void gemm_nl(
    const void* __restrict__ Ap,
    const float* __restrict__ Pm, const int* __restrict__ span,
    const float* __restrict__ rel, const int* __restrict__ lst,
    const int* __restrict__ offarr, const int* __restrict__ srcv,
    const u16* __restrict__ s2tab, int dst0, int dpc,
    const float* __restrict__ B, int ldb, const float* __restrict__ bias,
    void* __restrict__ Cp, int Cstride, int coff, int M, int NT) {
  constexpr int LDA = 264, LDB = 136;
  __shared__ u16 As[64 * LDA];
  __shared__ u16 Bs[64 * LDB];
  int e_start = 0, eM = M;
  if (AMODE == 2) {
    e_start = dst0 ? offarr[dst0 - 1] : 0;
    int len = offarr[dst0 + dpc - 1] - e_start;
    eM = len < M ? len : M;
  }
  const int m0 = blockIdx.x * 64;
  if (m0 >= eM) return;
  const int nbase = blockIdx.y * NT * 64;
  const int t = threadIdx.x;
  const int wave = t >> 6, lane = t & 63, lrow = lane & 15, quad = lane >> 4;

  // ---- stage As full-K (2048 8-elem chunks / 256 threads = 8 iters) ----
#pragma unroll
  for (int i = 0; i < 8; i++) {
    int c = t + i * 256;
    int row = c >> 5, col = (c & 31) * 8;
    int gm = m0 + row;
    uint4 va; va.x = va.y = va.z = va.w = 0u;
    if (gm < eM) {
      if (AMODE == 0) {
        if (ASRC == 0) {
          const float* af = (const float*)Ap + (size_t)gm * 256 + col;
          va = pack8(*(const float4*)af, *(const float4*)(af + 4));
        } else {
          va = *(const uint4*)((const u16*)Ap + (size_t)gm * 256 + col);
        }
      } else {
        int e = lst[e_start + gm];
        int xx = span[2 * e], yy = span[2 * e + 1];
        float sc = rel[e] / (float)(yy - xx);
        const float* py = Pm + (size_t)yy * 256 + col;
        const float* px = Pm + (size_t)xx * 256 + col;
        float4 ya = *(const float4*)py, yb = *(const float4*)(py + 4);
        float4 xa = *(const float4*)px, xb = *(const float4*)(px + 4);
        float4 d0 = {(ya.x - xa.x) * sc, (ya.y - xa.y) * sc,
                     (ya.z - xa.z) * sc, (ya.w - xa.w) * sc};
        float4 d1 = {(yb.x - xb.x) * sc, (yb.y - xb.y) * sc,
                     (yb.z - xb.z) * sc, (yb.w - xb.w) * sc};
        va = pack8(d0, d1);
      }
    }
    *(uint4*)&As[row * LDA + col] = va;
  }

  for (int nt = 0; nt < NT; nt++) {
    const int n0 = nbase + nt * 64;
    f32x4 acc[4] = {{0.f, 0.f, 0.f, 0.f}, {0.f, 0.f, 0.f, 0.f},
                    {0.f, 0.f, 0.f, 0.f}, {0.f, 0.f, 0.f, 0.f}};
    for (int k2 = 0; k2 < 2; k2++) {
      __syncthreads();  // As visible (nt=0); prior Bs reads done
#pragma unroll
      for (int i = 0; i < 4; i++) {
        int c = t + i * 256;
        int row = c >> 4, col = (c & 15) * 8;
        const float* bf = B + (size_t)(n0 + row) * ldb + k2 * 128 + col;
        uint4 vb = pack8(*(const float4*)bf, *(const float4*)(bf + 4));
        *(uint4*)&Bs[row * LDB + col] = vb;
      }
      __syncthreads();
      const u16* ab = &As[(wave * 16 + lrow) * LDA + k2 * 128 + quad * 8];
      const u16* bb = &Bs[lrow * LDB + quad * 8];
#pragma unroll
      for (int kk = 0; kk < 128; kk += 32) {
        bf16x8 av = *(const bf16x8*)(ab + kk);
#pragma unroll
        for (int j = 0; j < 4; j++) {
          bf16x8 bv = *(const bf16x8*)(bb + j * 16 * LDB + kk);
          acc[j] = __builtin_amdgcn_mfma_f32_16x16x32_bf16(av, bv, acc[j], 0, 0, 0);
        }
      }
    }
    // epilogue: C/D layout col = lane&15, row = quad*4 + reg
#pragma unroll
    for (int r = 0; r < 4; r++) {
      int m = m0 + wave * 16 + quad * 4 + r;
      if (m < eM) {
        float resv = 0.f;
        const u16* srow = nullptr;
        if (AMODE == 2) {
          int e = lst[e_start + m];
          srow = s2tab + (size_t)srcv[e] * 512;
        }
#pragma unroll
        for (int j = 0; j < 4; j++) {
          int n = n0 + j * 16 + lrow;
          float v = acc[j][r] + (bias ? bias[n] : 0.f);
          if (AMODE == 2) v += us2f(srow[n]);
          (void)resv;
          if (OUTBF) ((u16*)Cp)[(size_t)m * Cstride + coff + n] = f2us(v);
          else       ((float*)Cp)[(size_t)m * Cstride + coff + n] = v;
        }
      }
    }
  }
}

// ---------------- segment softmax aggregations -----------------------------
__global__ __launch_bounds__(256) void agg_ts(
    const int* __restrict__ off, const int* __restrict__ list,
    const int* __restrict__ src, const u16* __restrict__ a_src,
    const u16* __restrict__ a_dst, const u16* __restrict__ u_tok,
    float* __restrict__ out) {
  int i = blockIdx.x, d = threadIdx.x;
  int s0 = i ? off[i - 1] : 0, s1 = off[i];
  float ad = us2f(a_dst[(size_t)i * 256 + d]);
  float num = 0.f, den = 0.f;
  for (int p = s0; p < s1; p++) {
    int s = src[list[p]];
    float v = us2f(a_src[(size_t)s * 256 + d]) + ad;
    v = v >= 0.f ? v : 0.01f * v;
    float ex = __expf(v);
    den += ex;
    num += ex * us2f(u_tok[(size_t)s * 256 + d]);
  }
  out[(size_t)i * 256 + d] = num / fmaxf(den, 1e-9f);
}

// EE: buf rows chunk-local [m_ee(256) | attpre(256)] bf16
__global__ __launch_bounds__(256) void agg_ee_chunk(
    const int* __restrict__ off, const u16* __restrict__ buf,
    const u16* __restrict__ adp, float* __restrict__ out, int dst0) {
  int i = dst0 + blockIdx.x, d = threadIdx.x;
  int e_start = dst0 ? off[dst0 - 1] : 0;
  int s0 = i ? off[i - 1] : 0, s1 = off[i];
  float ad = us2f(adp[(size_t)i * 256 + d]);
  float num = 0.f, den = 0.f;
  for (int p = s0; p < s1; p++) {
    size_t row = (size_t)(p - e_start) * 512;
    float v = us2f(buf[row + 256 + d]) + ad;
    v = v >= 0.f ? v : 0.01f * v;
    float ex = __expf(v);
    den += ex;
    num += ex * us2f(buf[row + d]);
  }
  out[(size_t)i * 256 + d] = num / fmaxf(den, 1e-9f);
}

// GRU per edge + segment sum; gi bf16 by src, gh bf16 chunk-local by dst.
__global__ __launch_bounds__(256) void agg_gru(
    const int* __restrict__ off, const int* __restrict__ list,
    const int* __restrict__ src, const u16* __restrict__ gi,
    const u16* __restrict__ ghc, const float* __restrict__ feat,
    u16* __restrict__ out, int tok0) {
  int i = tok0 + blockIdx.x, d = threadIdx.x;
  int s0 = i ? off[i - 1] : 0, s1 = off[i];
  size_t b = (size_t)blockIdx.x * 768;
  float ghr = us2f(ghc[b + d]), ghz = us2f(ghc[b + 256 + d]), ghn = us2f(ghc[b + 512 + d]);
  float h = feat[(size_t)i * 256 + d];
  float sum = 0.f;
  for (int p = s0; p < s1; p++) {
    int s = src[list[p]];
    size_t g = (size_t)s * 768;
    float r = sigm(us2f(gi[g + d]) + ghr);
    float z = sigm(us2f(gi[g + 256 + d]) + ghz);
    float n = tanh_f(us2f(gi[g + 512 + d]) + r * ghn);
    sum += (1.f - z) * n + z * h;
  }
  out[(size_t)i * 256 + d] = f2us(sum);
}

// node GRU combine; gi/gh chunk-local f32, hprev bf16 global.
template <bool OUTBF>
__global__ __launch_bounds__(256) void gru_combine(
    const float* __restrict__ gi, const float* __restrict__ gh,
    const u16* __restrict__ hprev, void* __restrict__ out, int row0) {
  int i = blockIdx.x, d = threadIdx.x;
  size_t g = (size_t)i * 768;
  float h = us2f(hprev[(size_t)(row0 + i) * 256 + d]);
  float r = sigm(gi[g + d] + gh[g + d]);
  float z = sigm(gi[g + 256 + d] + gh[g + 256 + d]);
  float n = tanh_f(gi[g + 512 + d] + r * gh[g + 512 + d]);
  float v = (1.f - z) * n + z * h;
  if (OUTBF) ((u16*)out)[(size_t)(row0 + i) * 256 + d] = f2us(v);
  else       ((float*)out)[(size_t)(row0 + i) * 256 + d] = v;
}

// ---------------------------------------------------------------------------
extern "C" void kernel_launch(void* const* d_in, const int* in_sizes, int n_in,
                              void* d_out, int out_size, void* d_ws, size_t ws_size,
                              hipStream_t stream) {
  const float* feat_tok = (const float*)d_in[0];
  const float* feat_srl = (const float*)d_in[1];
  const float* feat_ent = (const float*)d_in[2];
  const float* bert     = (const float*)d_in[3];
  const float* rel_type = (const float*)d_in[4];
  const int* src_ts = (const int*)d_in[5];
  const int* dst_ts = (const int*)d_in[6];
  const int* src_ee = (const int*)d_in[7];
  const int* dst_ee = (const int*)d_in[8];
  const int* src_st = (const int*)d_in[9];
  const int* dst_st = (const int*)d_in[10];
  const int* src_et = (const int*)d_in[11];
  const int* dst_et = (const int*)d_in[12];
  const int* span   = (const int*)d_in[13];
  const float* Wn   = (const float*)d_in[14];
  const float* bn   = (const float*)d_in[15];
  const float* Watt = (const float*)d_in[16];  // 256 x 512 : [A1 | A2]
  const float* batt = (const float*)d_in[17];
  const float* Wrel = (const float*)d_in[18];  // 256 x 512 : [Wr1 | Wr2]
  const float* brel = (const float*)d_in[19];
  const float* Wc   = (const float*)d_in[20];
  const float* bc   = (const float*)d_in[21];
  const float* Wih  = (const float*)d_in[22];  // 768 x 256
  const float* Whh  = (const float*)d_in[23];
  const float* bih  = (const float*)d_in[24];
  const float* bhh  = (const float*)d_in[25];

  // ---- workspace overlays -------------------------------------------------
  char* W = (char*)d_ws;
  float* Pm    = (float*)(W + 0);                  // P0-P2: 51,201,024
  u16* u_tok   = (u16*)(W + 51250240);             // P1: 25.6M
  u16* a_src   = (u16*)(W + 76850240);             // P1: 25.6M
  u16* p_srl   = (u16*)(W + 102450240);            // P1: 10.24M
  u16* a_dst   = (u16*)(W + 112690240);            // P1: 10.24M
  u16* s_ent   = (u16*)(W + 51250240);             // P2 (TS dead): 5.12M
  u16* p_ent   = (u16*)(W + 56370240);             // P2: 5.12M
  u16* meeatt  = (u16*)(W + 51250240);             // P2 chunks: 40.96M used
  float* WW    = (float*)(W + 138000000);          // P2: 524,288
  float* B2    = (float*)(W + 138600000);          // P2: 262,144
  float* bias2 = (float*)(W + 138900000);          // P2: 1,024
  u16* s2tab   = (u16*)(W + 139000000);            // P2: 10.24M
  u16* adp     = (u16*)(W + 149300032);            // P2: 5.12M
  float* bsum  = (float*)(W + 155000000);          // P0: 800,768 (cumsum)
  u16* gi_srl  = (u16*)(W + 0);                    // P3 (Pm dead): 30.72M
  u16* gi_ent  = (u16*)(W + 30720000);             // P3: 15.36M
  u16* ghc     = (u16*)(W + 51250240);             // P3: 38.4M
  u16* hst     = (u16*)(W + 115300096);            // P3->P4: 25.6M
  u16* het     = (u16*)(W + 140900096);            // P3->P4: 25.6M
  float* giA   = (float*)(W + 0);                  // P4/P5: 38.4M
  float* ghA   = (float*)(W + 38400000);           // P4/P5: 38.4M
  u16* h1      = (u16*)(W + 76800000);             // P4->P5: 25.6M
  int* ts_off = (int*)(W + 166500096);
  int* ts_lst = (int*)(W + 166580096);
  int* ee_off = (int*)(W + 167780096);
  int* ee_lst = (int*)(W + 167820096);
  int* st_off = (int*)(W + 168420096);
  int* st_lst = (int*)(W + 168620096);
  int* et_off = (int*)(W + 169820096);
  int* et_lst = (int*)(W + 170020096);
  constexpr size_t NEED = 170620096;

  float* out_htok = (float*)d_out;
  float* out_hsrl = (float*)d_out + 12800000;
  float* out_hent = (float*)d_out + 17920000;

  if (ws_size < NEED) {  // sentinel: absmax ~= 1000 + ws_MB
    fill_sent<<<(out_size + 255) / 256, 256, 0, stream>>>(
        (float*)d_out, out_size, 1000.f + (float)(ws_size >> 20));
    return;
  }

  // ---- CSR builds ---------------------------------------------------------
  hipMemsetAsync(ts_off, 0, 20000 * 4, stream);
  hipMemsetAsync(ee_off, 0, 10000 * 4, stream);
  hipMemsetAsync(st_off, 0, 50000 * 4, stream);
  hipMemsetAsync(et_off, 0, 50000 * 4, stream);
  count_k<<<1172, 256, 0, stream>>>(dst_ts, 300000, ts_off);
  count_k<<<586, 256, 0, stream>>>(dst_ee, 150000, ee_off);
  count_k<<<1172, 256, 0, stream>>>(dst_st, 300000, st_off);
  count_k<<<586, 256, 0, stream>>>(dst_et, 150000, et_off);
  scan4_k<<<4, 1024, 0, stream>>>(ts_off, 20000, ee_off, 10000, st_off, 50000, et_off, 50000);
  fill_k<<<1172, 256, 0, stream>>>(dst_ts, 300000, ts_off, ts_lst);
  fill_k<<<586, 256, 0, stream>>>(dst_ee, 150000, ee_off, ee_lst);
  fill_k<<<1172, 256, 0, stream>>>(dst_st, 300000, st_off, st_lst);
  fill_k<<<586, 256, 0, stream>>>(dst_et, 150000, et_off, et_lst);

  cumsum_p1<<<782, 256, 0, stream>>>(bert, bsum);
  cumsum_p2p<<<256, 256, 0, stream>>>(bsum, 782);
  cumsum_p3<<<782, 256, 0, stream>>>(bert, bsum, Pm);
  make_B2<<<256, 256, 0, stream>>>(Watt, Wc, B2);
  make_bias2<<<1, 256, 0, stream>>>(Watt, bc, bias2);
  make_WW<<<512, 256, 0, stream>>>(Wc, B2, Wrel, WW);

  // ---- P1: TS attention -> h_srl ------------------------------------------
  gemm_nl<0, 0, true><<<dim3(782, 1), 256, 0, stream>>>(
      feat_tok, nullptr, nullptr, nullptr, nullptr, nullptr, nullptr, nullptr, 0, 0,
      Wn, 256, bn, u_tok, 256, 0, 50000, 4);
  gemm_nl<0, 1, true><<<dim3(782, 1), 256, 0, stream>>>(
      u_tok, nullptr, nullptr, nullptr, nullptr, nullptr, nullptr, nullptr, 0, 0,
      Watt, 512, nullptr, a_src, 256, 0, 50000, 4);
  gemm_nl<0, 0, true><<<dim3(313, 2), 256, 0, stream>>>(
      feat_srl, nullptr, nullptr, nullptr, nullptr, nullptr, nullptr, nullptr, 0, 0,
      Wn, 256, bn, p_srl, 256, 0, 20000, 2);
  gemm_nl<0, 1, true><<<dim3(313, 2), 256, 0, stream>>>(
      p_srl, nullptr, nullptr, nullptr, nullptr, nullptr, nullptr, nullptr, 0, 0,
      Watt + 256, 512, batt, a_dst, 256, 0, 20000, 2);
  agg_ts<<<20000, 256, 0, stream>>>(ts_off, ts_lst, src_ts, a_src, a_dst, u_tok, out_hsrl);

  // ---- P2: EE attention -> h_ent ------------------------------------------
  gemm_nl<0, 0, true><<<dim3(157, 2), 256, 0, stream>>>(
      feat_ent, nullptr, nullptr, nullptr, nullptr, nullptr, nullptr, nullptr, 0, 0,
      Wrel, 512, brel, s_ent, 256, 0, 10000, 2);
  gemm_nl<0, 0, true><<<dim3(157, 2), 256, 0, stream>>>(
      feat_ent, nullptr, nullptr, nullptr, nullptr, nullptr, nullptr, nullptr, 0, 0,
      Wn, 256, bn, p_ent, 256, 0, 10000, 2);
  gemm_nl<0, 1, true><<<dim3(157, 2), 256, 0, stream>>>(
      s_ent, nullptr, nullptr, nullptr, nullptr, nullptr, nullptr, nullptr, 0, 0,
      Wc, 256, bc, s2tab, 512, 0, 10000, 2);
  gemm_nl<0, 1, true><<<dim3(157, 2), 256, 0, stream>>>(
      s_ent, nullptr, nullptr, nullptr, nullptr, nullptr, nullptr, nullptr, 0, 0,
      B2, 256, bias2, s2tab, 512, 256, 10000, 2);
  gemm_nl<0, 1, true><<<dim3(157, 2), 256, 0, stream>>>(
      p_ent, nullptr, nullptr, nullptr, nullptr, nullptr, nullptr, nullptr, 0, 0,
      Watt + 256, 512, batt, adp, 256, 0, 10000, 2);
  for (int c = 0; c < 4; c++) {  // 2500 dsts x exactly 15 edges = 37500
    gemm_nl<2, 0, true><<<dim3(625, 1), 256, 0, stream>>>(
        nullptr, Pm, span, rel_type, ee_lst, ee_off, src_ee, s2tab, c * 2500, 2500,
        WW, 256, nullptr, meeatt, 512, 0, 40000, 8);
    agg_ee_chunk<<<2500, 256, 0, stream>>>(ee_off, meeatt, adp, out_hent, c * 2500);
  }

  // ---- P3: GRU gate tables + edge GRU aggregations ------------------------
  gemm_nl<0, 0, true><<<dim3(313, 3), 256, 0, stream>>>(
      out_hsrl, nullptr, nullptr, nullptr, nullptr, nullptr, nullptr, nullptr, 0, 0,
      Wih, 256, bih, gi_srl, 768, 0, 20000, 4);
  gemm_nl<0, 0, true><<<dim3(157, 3), 256, 0, stream>>>(
      out_hent, nullptr, nullptr, nullptr, nullptr, nullptr, nullptr, nullptr, 0, 0,
      Wih, 256, bih, gi_ent, 768, 0, 10000, 4);
  for (int c = 0; c < 2; c++) {  // gh chunks of 25000 tokens
    int base = c * 25000;
    gemm_nl<0, 0, true><<<dim3(391, 3), 256, 0, stream>>>(
        feat_tok + (size_t)base * 256, nullptr, nullptr, nullptr, nullptr, nullptr,
        nullptr, nullptr, 0, 0, Whh, 256, bhh, ghc, 768, 0, 25000, 4);
    agg_gru<<<25000, 256, 0, stream>>>(st_off, st_lst, src_st, gi_srl, ghc, feat_tok, hst, base);
    agg_gru<<<25000, 256, 0, stream>>>(et_off, et_lst, src_et, gi_ent, ghc, feat_tok, het, base);
  }

  // ---- P4: h1 = GRU(x=h_ent_tok, h=h_srl_tok), 4 x 12500 rows -------------
  for (int c = 0; c < 4; c++) {
    int base = c * 12500;
    gemm_nl<0, 1, false><<<dim3(196, 3), 256, 0, stream>>>(
        het + (size_t)base * 256, nullptr, nullptr, nullptr, nullptr, nullptr,
        nullptr, nullptr, 0, 0, Wih, 256, bih, giA, 768, 0, 12500, 4);
    gemm_nl<0, 1, false><<<dim3(196, 3), 256, 0, stream>>>(
        hst + (size_t)base * 256, nullptr, nullptr, nullptr, nullptr, nullptr,
        nullptr, nullptr, 0, 0, Whh, 256, bhh, ghA, 768, 0, 12500, 4);
    gru_combine<true><<<12500, 256, 0, stream>>>(giA, ghA, hst, h1, base);
  }
  // ---- P5: h_tok = GRU(x=feat_tok, h=h1) ----------------------------------
  for (int c = 0; c < 4; c++) {
    int base = c * 12500;
    gemm_nl<0, 0, false><<<dim3(196, 3), 256, 0, stream>>>(
        feat_tok + (size_t)base * 256, nullptr, nullptr, nullptr, nullptr, nullptr,
        nullptr, nullptr, 0, 0, Wih, 256, bih, giA, 768, 0, 12500, 4);
    gemm_nl<0, 1, false><<<dim3(196, 3), 256, 0, stream>>>(
        h1 + (size_t)base * 256, nullptr, nullptr, nullptr, nullptr, nullptr,
        nullptr, nullptr, 0, 0, Whh, 256, bhh, ghA, 768, 0, 12500, 4);
    gru_combine<false><<<12500, 256, 0, stream>>>(giA, ghA, h1, out_htok, base);
  }
}

// Round 2
// 1914.326 us; speedup vs baseline: 1.2031x; 1.1095x over previous
//
#include <hip/hip_runtime.h>
#include <stdint.h>

// ---------------------------------------------------------------------------
// HeteroRGCNLayer on MI355X. Inputs/outputs float32; MFMA compute in bf16.
// D=256, N_TOK=50000, N_SRL=20000, N_ENT=10000, T=50000
// E_TS=300000, E_EE=150000, E_ST=300000, E_ET=150000
// R5: cumsum_p2 parallelized (188us -> ~4us).
// R6: (a) all GEMM B-operands pre-converted to bf16 once (conv8) -> Bs staging
//     is a pure uint4 copy (was pack8 = ~2x MFMA cycles in VALU);
//     (b) agg_* kernels: wave-per-edge, ushort4 loads, LDS-staged indices,
//     cross-wave LDS reduce; a_src/u_tok packed into one 1KB row (uta).
//     bf16 weights live in d_out tail (only overwritten by final P5 combine).
// ---------------------------------------------------------------------------

typedef unsigned short u16;
typedef __bf16 bf16_t;
typedef bf16_t bf16x8 __attribute__((ext_vector_type(8)));
typedef float f32x4 __attribute__((ext_vector_type(4)));

__device__ __forceinline__ float us2f(u16 h) {
  unsigned int u = ((unsigned int)h) << 16;
  return __builtin_bit_cast(float, u);
}
__device__ __forceinline__ u16 f2us(float f) {  // RNE float->bf16
  unsigned int u = __builtin_bit_cast(unsigned int, f);
  u += 0x7FFFu + ((u >> 16) & 1u);
  return (u16)(u >> 16);
}
__device__ __forceinline__ uint4 pack8(float4 a, float4 b) {
  uint4 v;
  v.x = f2us(a.x) | ((unsigned)f2us(a.y) << 16);
  v.y = f2us(a.z) | ((unsigned)f2us(a.w) << 16);
  v.z = f2us(b.x) | ((unsigned)f2us(b.y) << 16);
  v.w = f2us(b.z) | ((unsigned)f2us(b.w) << 16);
  return v;
}
__device__ __forceinline__ void us2f4(ushort4 v, float* o) {
  o[0] = us2f(v.x); o[1] = us2f(v.y); o[2] = us2f(v.z); o[3] = us2f(v.w);
}
__device__ __forceinline__ float sigm(float x) { return 1.f / (1.f + __expf(-x)); }
__device__ __forceinline__ float tanh_f(float x) {
  x = fminf(fmaxf(x, -15.f), 15.f);
  float e = __expf(2.f * x);
  return (e - 1.f) / (e + 1.f);
}

// ---------------- diagnostics ---------------------------------------------
__global__ void fill_sent(float* out, int n, float v) {
  int i = blockIdx.x * 256 + threadIdx.x;
  if (i < n) out[i] = v;
}

// ---------------- CSR build ------------------------------------------------
__global__ void count_k(const int* __restrict__ dst, int E, int* __restrict__ cnt) {
  int i = blockIdx.x * 256 + threadIdx.x;
  if (i < E) atomicAdd(&cnt[dst[i]], 1);
}

__global__ __launch_bounds__(1024) void scan4_k(int* a0, int n0, int* a1, int n1,
                                                int* a2, int n2, int* a3, int n3) {
  int* a; int n;
  if (blockIdx.x == 0) { a = a0; n = n0; }
  else if (blockIdx.x == 1) { a = a1; n = n1; }
  else if (blockIdx.x == 2) { a = a2; n = n2; }
  else { a = a3; n = n3; }
  __shared__ int swv[16];
  const int t = threadIdx.x, lane = t & 63, wid = t >> 6;
  int carry = 0;
  for (int base = 0; base < n; base += 1024) {
    int r = base + t;
    int v = (r < n) ? a[r] : 0;
    int inc = v;
#pragma unroll
    for (int o = 1; o < 64; o <<= 1) {
      int x = __shfl_up(inc, o, 64);
      if (lane >= o) inc += x;
    }
    if (lane == 63) swv[wid] = inc;
    __syncthreads();
    int wbase = 0, tot = 0;
    for (int w = 0; w < 16; w++) { int s = swv[w]; tot += s; if (w < wid) wbase += s; }
    if (r < n) a[r] = carry + wbase + inc - v;  // exclusive prefix
    carry += tot;
    __syncthreads();
  }
}

__global__ void fill_k(const int* __restrict__ dst, int E, int* __restrict__ off,
                       int* __restrict__ list) {
  int i = blockIdx.x * 256 + threadIdx.x;
  if (i < E) {
    int p = atomicAdd(&off[dst[i]], 1);
    list[p] = i;
  }
}

// ---------------- coalesced 3-pass prefix sum of bert emb ------------------
__global__ __launch_bounds__(256) void cumsum_p1(const float* __restrict__ emb,
                                                 float* __restrict__ bsum) {
  int b = blockIdx.x, t = threadIdx.x;
  int r0 = b * 64, r1 = min(r0 + 64, 50000);
  float acc = 0.f;
  for (int r = r0; r < r1; r++) acc += emb[(size_t)r * 256 + t];
  bsum[(size_t)b * 256 + t] = acc;
}
// parallel in-place exclusive scan of bsum along the block axis.
__global__ __launch_bounds__(256) void cumsum_p2p(float* __restrict__ bsum, int nb) {
  const int d = blockIdx.x;
  const int t = threadIdx.x, lane = t & 63, wid = t >> 6;
  __shared__ float wsum[4];
  float v[4];
  float s = 0.f;
#pragma unroll
  for (int j = 0; j < 4; j++) {
    int b = t * 4 + j;
    v[j] = (b < nb) ? bsum[(size_t)b * 256 + d] : 0.f;
    s += v[j];
  }
  float inc = s;
#pragma unroll
  for (int o = 1; o < 64; o <<= 1) {
    float x = __shfl_up(inc, o, 64);
    if (lane >= o) inc += x;
  }
  if (lane == 63) wsum[wid] = inc;
  __syncthreads();
  float wbase = 0.f;
  for (int w = 0; w < 4; w++) {
    float ws = wsum[w];
    if (w < wid) wbase += ws;
  }
  float excl = wbase + inc - s;
#pragma unroll
  for (int j = 0; j < 4; j++) {
    int b = t * 4 + j;
    if (b < nb) bsum[(size_t)b * 256 + d] = excl;
    excl += v[j];
  }
}
__global__ __launch_bounds__(256) void cumsum_p3(const float* __restrict__ emb,
                                                 const float* __restrict__ bsum,
                                                 float* __restrict__ Pm) {
  int b = blockIdx.x, t = threadIdx.x;
  int r0 = b * 64, r1 = min(r0 + 64, 50000);
  float acc = bsum[(size_t)b * 256 + t];
  if (b == 0) Pm[t] = 0.f;
  for (int r = r0; r < r1; r++) {
    acc += emb[(size_t)r * 256 + t];
    Pm[(size_t)(r + 1) * 256 + t] = acc;
  }
}

// ---------------- derived weights (f32) ------------------------------------
__global__ __launch_bounds__(256) void make_B2(const float* __restrict__ Watt,
                                               const float* __restrict__ Wc,
                                               float* __restrict__ B2) {
  int r = blockIdx.x, k = threadIdx.x;
  float s = 0.f;
  for (int n = 0; n < 256; n++) s += Watt[r * 512 + n] * Wc[n * 256 + k];
  B2[r * 256 + k] = s;
}
__global__ void make_bias2(const float* __restrict__ Watt, const float* __restrict__ bc,
                           float* __restrict__ bias2) {
  int r = threadIdx.x;
  float s = 0.f;
  for (int k = 0; k < 256; k++) s += Watt[r * 512 + k] * bc[k];
  bias2[r] = s;
}
// WW (512x256): rows 0..255 = Wc@Wr2 ; rows 256..511 = B2@Wr2
__global__ __launch_bounds__(256) void make_WW(const float* __restrict__ Wc,
                                               const float* __restrict__ B2,
                                               const float* __restrict__ Wrel,
                                               float* __restrict__ WW) {
  int r = blockIdx.x, k = threadIdx.x;
  const float* X = (r < 256) ? (Wc + (size_t)r * 256) : (B2 + (size_t)(r - 256) * 256);
  float s = 0.f;
  for (int n = 0; n < 256; n++) s += X[n] * Wrel[(size_t)n * 512 + 256 + k];
  WW[(size_t)r * 256 + k] = s;
}

// ---------------- batched f32 -> bf16 weight conversion --------------------
__global__ __launch_bounds__(256) void conv8(
    const float* s0, u16* d0, int n0, const float* s1, u16* d1, int n1,
    const float* s2, u16* d2, int n2, const float* s3, u16* d3, int n3,
    const float* s4, u16* d4, int n4, const float* s5, u16* d5, int n5,
    const float* s6, u16* d6, int n6, const float* s7, u16* d7, int n7) {
  const float* s; u16* d; int n;
  switch (blockIdx.y) {
    case 0: s = s0; d = d0; n = n0; break;
    case 1: s = s1; d = d1; n = n1; break;
    case 2: s = s2; d = d2; n = n2; break;
    case 3: s = s3; d = d3; n = n3; break;
    case 4: s = s4; d = d4; n = n4; break;
    case 5: s = s5; d = d5; n = n5; break;
    case 6: s = s6; d = d6; n = n6; break;
    default: s = s7; d = d7; n = n7; break;
  }
  int i = (blockIdx.x * 256 + threadIdx.x) * 8;
  if (i < n) {
    float4 a = *(const float4*)(s + i), b = *(const float4*)(s + i + 4);
    *(uint4*)(d + i) = pack8(a, b);
  }
}

// ---------------------------------------------------------------------------
// N-loop GEMM: C[M x *] = A[M x 256] @ B^T + bias. B is pre-converted bf16.
// A staged ONCE in LDS (full K, 64 rows), then NT n-tiles of 64 cols looped.
// AMODE 0: A from memory (ASRC 0 = f32, 1 = bf16, row stride lda elements).
// AMODE 2: EE edges — row m is edge lst[e_start+m],
// A[k] = rel/(y-x)*(Pm[y][k]-Pm[x][k]); s2tab residual in epilogue.
// LDS: As 64x264x2B=33.8K + Bs 64x136x2B=17.4K = 51.2 KB -> 3 blocks/CU.
// ---------------------------------------------------------------------------
template <int AMODE, int ASRC, bool OUTBF>
__global__ __launch_bounds__(256) void gemm_nl(
    const void* __restrict__ Ap, int lda,
    const float* __restrict__ Pm, const int* __restrict__ span,
    const float* __restrict__ rel, const int* __restrict__ lst,
    const int* __restrict__ offarr, const int* __restrict__ srcv,
    const u16* __restrict__ s2tab, int dst0, int dpc,
    const u16* __restrict__ B, int ldb, const float* __restrict__ bias,
    void* __restrict__ Cp, int Cstride, int coff, int M, int NT) {
  constexpr int LDA = 264, LDB = 136;
  __shared__ u16 As[64 * LDA];
  __shared__ u16 Bs[64 * LDB];
  int e_start = 0, eM = M;
  if (AMODE == 2) {
    e_start = dst0 ? offarr[dst0 - 1] : 0;
    int len = offarr[dst0 + dpc - 1] - e_start;
    eM = len < M ? len : M;
  }
  const int m0 = blockIdx.x * 64;
  if (m0 >= eM) return;
  const int nbase = blockIdx.y * NT * 64;
  const int t = threadIdx.x;
  const int wave = t >> 6, lane = t & 63, lrow = lane & 15, quad = lane >> 4;

  // ---- stage As full-K (2048 8-elem chunks / 256 threads = 8 iters) ----
#pragma unroll
  for (int i = 0; i < 8; i++) {
    int c = t + i * 256;
    int row = c >> 5, col = (c & 31) * 8;
    int gm = m0 + row;
    uint4 va; va.x = va.y = va.z = va.w = 0u;
    if (gm < eM) {
      if (AMODE == 0) {
        if (ASRC == 0) {
          const float* af = (const float*)Ap + (size_t)gm * lda + col;
          va = pack8(*(const float4*)af, *(const float4*)(af + 4));
        } else {
          va = *(const uint4*)((const u16*)Ap + (size_t)gm * lda + col);
        }
      } else {
        int e = lst[e_start + gm];
        int xx = span[2 * e], yy = span[2 * e + 1];
        float sc = rel[e] / (float)(yy - xx);
        const float* py = Pm + (size_t)yy * 256 + col;
        const float* px = Pm + (size_t)xx * 256 + col;
        float4 ya = *(const float4*)py, yb = *(const float4*)(py + 4);
        float4 xa = *(const float4*)px, xb = *(const float4*)(px + 4);
        float4 d0 = {(ya.x - xa.x) * sc, (ya.y - xa.y) * sc,
                     (ya.z - xa.z) * sc, (ya.w - xa.w) * sc};
        float4 d1 = {(yb.x - xb.x) * sc, (yb.y - xb.y) * sc,
                     (yb.z - xb.z) * sc, (yb.w - xb.w) * sc};
        va = pack8(d0, d1);
      }
    }
    *(uint4*)&As[row * LDA + col] = va;
  }

  for (int nt = 0; nt < NT; nt++) {
    const int n0 = nbase + nt * 64;
    f32x4 acc[4] = {{0.f, 0.f, 0.f, 0.f}, {0.f, 0.f, 0.f, 0.f},
                    {0.f, 0.f, 0.f, 0.f}, {0.f, 0.f, 0.f, 0.f}};
    for (int k2 = 0; k2 < 2; k2++) {
      __syncthreads();  // As visible (nt=0); prior Bs reads done
#pragma unroll
      for (int i = 0; i < 4; i++) {
        int c = t + i * 256;
        int row = c >> 4, col = (c & 15) * 8;
        uint4 vb = *(const uint4*)(B + (size_t)(n0 + row) * ldb + k2 * 128 + col);
        *(uint4*)&Bs[row * LDB + col] = vb;
      }
      __syncthreads();
      const u16* ab = &As[(wave * 16 + lrow) * LDA + k2 * 128 + quad * 8];
      const u16* bb = &Bs[lrow * LDB + quad * 8];
#pragma unroll
      for (int kk = 0; kk < 128; kk += 32) {
        bf16x8 av = *(const bf16x8*)(ab + kk);
#pragma unroll
        for (int j = 0; j < 4; j++) {
          bf16x8 bv = *(const bf16x8*)(bb + j * 16 * LDB + kk);
          acc[j] = __builtin_amdgcn_mfma_f32_16x16x32_bf16(av, bv, acc[j], 0, 0, 0);
        }
      }
    }
    // epilogue: C/D layout col = lane&15, row = quad*4 + reg
#pragma unroll
    for (int r = 0; r < 4; r++) {
      int m = m0 + wave * 16 + quad * 4 + r;
      if (m < eM) {
        const u16* srow = nullptr;
        if (AMODE == 2) {
          int e = lst[e_start + m];
          srow = s2tab + (size_t)srcv[e] * 512;
        }
#pragma unroll
        for (int j = 0; j < 4; j++) {
          int n = n0 + j * 16 + lrow;
          float v = acc[j][r] + (bias ? bias[n] : 0.f);
          if (AMODE == 2) v += us2f(srow[n]);
          if (OUTBF) ((u16*)Cp)[(size_t)m * Cstride + coff + n] = f2us(v);
          else       ((float*)Cp)[(size_t)m * Cstride + coff + n] = v;
        }
      }
    }
  }
}

// ---------------- segment softmax aggregations (wave-per-edge) -------------
// uta row: [u_tok(256) | a_src(256)] bf16 = 1KB. Lane owns 4 dims; wave w
// handles edges w, w+4, ...; cross-wave reduce in LDS.
__global__ __launch_bounds__(256) void agg_ts2(
    const int* __restrict__ off, const int* __restrict__ list,
    const int* __restrict__ src, const u16* __restrict__ uta,
    const u16* __restrict__ adst, float* __restrict__ out) {
  const int i = blockIdx.x, t = threadIdx.x, lane = t & 63, w = t >> 6;
  const int s0 = i ? off[i - 1] : 0, s1 = off[i];
  const int cnt = s1 - s0;  // == 15 (covering dst)
  __shared__ int sl[64];
  __shared__ float nbuf[4][256], dbuf[4][256];
  if (t < cnt) sl[t] = src[list[s0 + t]];
  __syncthreads();
  const int d4 = lane * 4;
  float ad[4];
  us2f4(*(const ushort4*)&adst[(size_t)i * 256 + d4], ad);
  float num[4] = {0.f, 0.f, 0.f, 0.f}, den[4] = {0.f, 0.f, 0.f, 0.f};
  for (int p = w; p < cnt; p += 4) {
    const u16* row = uta + (size_t)sl[p] * 512;
    float u[4], a[4];
    us2f4(*(const ushort4*)&row[d4], u);
    us2f4(*(const ushort4*)&row[256 + d4], a);
#pragma unroll
    for (int j = 0; j < 4; j++) {
      float v = a[j] + ad[j];
      v = v >= 0.f ? v : 0.01f * v;
      float ex = __expf(v);
      den[j] += ex;
      num[j] += ex * u[j];
    }
  }
#pragma unroll
  for (int j = 0; j < 4; j++) { nbuf[w][d4 + j] = num[j]; dbuf[w][d4 + j] = den[j]; }
  __syncthreads();
  float ns = nbuf[0][t] + nbuf[1][t] + nbuf[2][t] + nbuf[3][t];
  float ds = dbuf[0][t] + dbuf[1][t] + dbuf[2][t] + dbuf[3][t];
  out[(size_t)i * 256 + t] = ns / fmaxf(ds, 1e-9f);
}

// EE: buf rows chunk-local [m_ee(256) | attpre(256)] bf16, p-contiguous.
__global__ __launch_bounds__(256) void agg_ee2(
    const int* __restrict__ off, const u16* __restrict__ buf,
    const u16* __restrict__ adp, float* __restrict__ out, int dst0) {
  const int i = dst0 + blockIdx.x, t = threadIdx.x, lane = t & 63, w = t >> 6;
  const int e_start = dst0 ? off[dst0 - 1] : 0;
  const int s0 = i ? off[i - 1] : 0, s1 = off[i];
  __shared__ float nbuf[4][256], dbuf[4][256];
  const int d4 = lane * 4;
  float ad[4];
  us2f4(*(const ushort4*)&adp[(size_t)i * 256 + d4], ad);
  float num[4] = {0.f, 0.f, 0.f, 0.f}, den[4] = {0.f, 0.f, 0.f, 0.f};
  for (int p = s0 + w; p < s1; p += 4) {
    const u16* row = buf + (size_t)(p - e_start) * 512;
    float m[4], a[4];
    us2f4(*(const ushort4*)&row[d4], m);
    us2f4(*(const ushort4*)&row[256 + d4], a);
#pragma unroll
    for (int j = 0; j < 4; j++) {
      float v = a[j] + ad[j];
      v = v >= 0.f ? v : 0.01f * v;
      float ex = __expf(v);
      den[j] += ex;
      num[j] += ex * m[j];
    }
  }
#pragma unroll
  for (int j = 0; j < 4; j++) { nbuf[w][d4 + j] = num[j]; dbuf[w][d4 + j] = den[j]; }
  __syncthreads();
  float ns = nbuf[0][t] + nbuf[1][t] + nbuf[2][t] + nbuf[3][t];
  float ds = dbuf[0][t] + dbuf[1][t] + dbuf[2][t] + dbuf[3][t];
  out[(size_t)i * 256 + t] = ns / fmaxf(ds, 1e-9f);
}

// GRU per edge + segment sum; gi bf16 by src (768/row), gh bf16 chunk-local.
__global__ __launch_bounds__(256) void agg_gru2(
    const int* __restrict__ off, const int* __restrict__ list,
    const int* __restrict__ src, const u16* __restrict__ gi,
    const u16* __restrict__ ghc, const float* __restrict__ feat,
    u16* __restrict__ out, int tok0) {
  const int bi = blockIdx.x, i = tok0 + bi;
  const int t = threadIdx.x, lane = t & 63, w = t >> 6;
  const int s0 = i ? off[i - 1] : 0, s1 = off[i];
  const int cnt = s1 - s0;  // 6 (st) / 3 (et), covering dst
  __shared__ int sl[32];
  __shared__ float red[4][256];
  if (t < cnt) sl[t] = src[list[s0 + t]];
  __syncthreads();
  const int d4 = lane * 4;
  const size_t b = (size_t)bi * 768;
  float ghr[4], ghz[4], ghn[4], h[4];
  us2f4(*(const ushort4*)&ghc[b + d4], ghr);
  us2f4(*(const ushort4*)&ghc[b + 256 + d4], ghz);
  us2f4(*(const ushort4*)&ghc[b + 512 + d4], ghn);
  { float4 v = *(const float4*)&feat[(size_t)i * 256 + d4];
    h[0] = v.x; h[1] = v.y; h[2] = v.z; h[3] = v.w; }
  float sum[4] = {0.f, 0.f, 0.f, 0.f};
  for (int p = w; p < cnt; p += 4) {
    const u16* g = gi + (size_t)sl[p] * 768;
    float gr[4], gz[4], gn[4];
    us2f4(*(const ushort4*)&g[d4], gr);
    us2f4(*(const ushort4*)&g[256 + d4], gz);
    us2f4(*(const ushort4*)&g[512 + d4], gn);
#pragma unroll
    for (int j = 0; j < 4; j++) {
      float r = sigm(gr[j] + ghr[j]);
      float z = sigm(gz[j] + ghz[j]);
      float n = tanh_f(gn[j] + r * ghn[j]);
      sum[j] += (1.f - z) * n + z * h[j];
    }
  }
#pragma unroll
  for (int j = 0; j < 4; j++) red[w][d4 + j] = sum[j];
  __syncthreads();
  float s = red[0][t] + red[1][t] + red[2][t] + red[3][t];
  out[(size_t)i * 256 + t] = f2us(s);
}

// node GRU combine; 4 rows per block (wave w -> row), float4 loads.
template <bool OUTBF>
__global__ __launch_bounds__(256) void gru_combine2(
    const float* __restrict__ gi, const float* __restrict__ gh,
    const u16* __restrict__ hprev, void* __restrict__ out, int row0) {
  const int t = threadIdx.x, lane = t & 63, w = t >> 6;
  const int li = blockIdx.x * 4 + w;  // chunk-local row
  const int d4 = lane * 4;
  const size_t g = (size_t)li * 768;
  float4 ir = *(const float4*)&gi[g + d4];
  float4 hr4 = *(const float4*)&gh[g + d4];
  float4 iz = *(const float4*)&gi[g + 256 + d4];
  float4 hz4 = *(const float4*)&gh[g + 256 + d4];
  float4 in4 = *(const float4*)&gi[g + 512 + d4];
  float4 hn4 = *(const float4*)&gh[g + 512 + d4];
  float h[4];
  us2f4(*(const ushort4*)&hprev[(size_t)(row0 + li) * 256 + d4], h);
  float gir[4] = {ir.x, ir.y, ir.z, ir.w}, ghr[4] = {hr4.x, hr4.y, hr4.z, hr4.w};
  float giz[4] = {iz.x, iz.y, iz.z, iz.w}, ghz[4] = {hz4.x, hz4.y, hz4.z, hz4.w};
  float gin[4] = {in4.x, in4.y, in4.z, in4.w}, ghn[4] = {hn4.x, hn4.y, hn4.z, hn4.w};
  float o[4];
#pragma unroll
  for (int j = 0; j < 4; j++) {
    float r = sigm(gir[j] + ghr[j]);
    float z = sigm(giz[j] + ghz[j]);
    float n = tanh_f(gin[j] + r * ghn[j]);
    o[j] = (1.f - z) * n + z * h[j];
  }
  if (OUTBF) {
    ushort4 ov = {f2us(o[0]), f2us(o[1]), f2us(o[2]), f2us(o[3])};
    *(ushort4*)&((u16*)out)[(size_t)(row0 + li) * 256 + d4] = ov;
  } else {
    float4 ov = {o[0], o[1], o[2], o[3]};
    *(float4*)&((float*)out)[(size_t)(row0 + li) * 256 + d4] = ov;
  }
}

// ---------------------------------------------------------------------------
extern "C" void kernel_launch(void* const* d_in, const int* in_sizes, int n_in,
                              void* d_out, int out_size, void* d_ws, size_t ws_size,
                              hipStream_t stream) {
  const float* feat_tok = (const float*)d_in[0];
  const float* feat_srl = (const float*)d_in[1];
  const float* feat_ent = (const float*)d_in[2];
  const float* bert     = (const float*)d_in[3];
  const float* rel_type = (const float*)d_in[4];
  const int* src_ts = (const int*)d_in[5];
  const int* dst_ts = (const int*)d_in[6];
  const int* src_ee = (const int*)d_in[7];
  const int* dst_ee = (const int*)d_in[8];
  const int* src_st = (const int*)d_in[9];
  const int* dst_st = (const int*)d_in[10];
  const int* src_et = (const int*)d_in[11];
  const int* dst_et = (const int*)d_in[12];
  const int* span   = (const int*)d_in[13];
  const float* Wn   = (const float*)d_in[14];
  const float* bn   = (const float*)d_in[15];
  const float* Watt = (const float*)d_in[16];  // 256 x 512 : [A1 | A2]
  const float* batt = (const float*)d_in[17];
  const float* Wrel = (const float*)d_in[18];  // 256 x 512 : [Wr1 | Wr2]
  const float* brel = (const float*)d_in[19];
  const float* Wc   = (const float*)d_in[20];
  const float* bc   = (const float*)d_in[21];
  const float* Wih  = (const float*)d_in[22];  // 768 x 256
  const float* Whh  = (const float*)d_in[23];
  const float* bih  = (const float*)d_in[24];
  const float* bhh  = (const float*)d_in[25];

  // ---- workspace overlays -------------------------------------------------
  char* W = (char*)d_ws;
  float* Pm    = (float*)(W + 0);                  // P0-P2: 51,201,024
  u16* uta     = (u16*)(W + 51250240);             // P1: 50000x512 bf16 = 51.2M
  u16* p_srl   = (u16*)(W + 102450240);            // P1: 10.24M
  u16* a_dst   = (u16*)(W + 112690240);            // P1: 10.24M
  u16* s_ent   = (u16*)(W + 51250240);             // P2 (TS dead): 5.12M
  u16* p_ent   = (u16*)(W + 56370240);             // P2: 5.12M
  u16* meeatt  = (u16*)(W + 51250240);             // P2 chunks: 40.96M used
  float* WW    = (float*)(W + 138000000);          // P2: 524,288
  float* B2    = (float*)(W + 138600000);          // P2: 262,144
  float* bias2 = (float*)(W + 138900000);          // P2: 1,024
  u16* s2tab   = (u16*)(W + 139000000);            // P2: 10.24M
  u16* adp     = (u16*)(W + 149300032);            // P2: 5.12M
  float* bsum  = (float*)(W + 155000000);          // P0: 800,768 (cumsum)
  u16* gi_srl  = (u16*)(W + 0);                    // P3 (Pm dead): 30.72M
  u16* gi_ent  = (u16*)(W + 30720000);             // P3: 15.36M
  u16* ghc     = (u16*)(W + 51250240);             // P3: 38.4M
  u16* hst     = (u16*)(W + 115300096);            // P3->P4: 25.6M
  u16* het     = (u16*)(W + 140900096);            // P3->P4: 25.6M
  float* giA   = (float*)(W + 0);                  // P4/P5: 38.4M
  float* ghA   = (float*)(W + 38400000);           // P4/P5: 38.4M
  u16* h1      = (u16*)(W + 76800000);             // P4->P5: 25.6M
  int* ts_off = (int*)(W + 166500096);
  int* ts_lst = (int*)(W + 166580096);
  int* ee_off = (int*)(W + 167780096);
  int* ee_lst = (int*)(W + 167820096);
  int* st_off = (int*)(W + 168420096);
  int* st_lst = (int*)(W + 168620096);
  int* et_off = (int*)(W + 169820096);
  int* et_lst = (int*)(W + 170020096);
  constexpr size_t NEED = 170620096;

  float* out_htok = (float*)d_out;
  float* out_hsrl = (float*)d_out + 12800000;
  float* out_hent = (float*)d_out + 17920000;

  // bf16 weights in d_out tail (bytes 49,000,000..50,966,080): inside the
  // rows written ONLY by the final P5 chunk-3 gru_combine2 (after last use).
  u16* wtb    = (u16*)((char*)d_out + 49000000);
  u16* Wn_b   = wtb;            // 65536
  u16* Watt_b = wtb + 65536;    // 131072
  u16* Wrel_b = wtb + 196608;   // 131072
  u16* Wc_b   = wtb + 327680;   // 65536
  u16* Wih_b  = wtb + 393216;   // 196608
  u16* Whh_b  = wtb + 589824;   // 196608
  u16* WW_b   = wtb + 786432;   // 131072
  u16* B2_b   = wtb + 917504;   // 65536 -> ends 50,966,080 < 51,200,000

  if (ws_size < NEED) {  // sentinel: absmax ~= 1000 + ws_MB
    fill_sent<<<(out_size + 255) / 256, 256, 0, stream>>>(
        (float*)d_out, out_size, 1000.f + (float)(ws_size >> 20));
    return;
  }

  // ---- CSR builds ---------------------------------------------------------
  hipMemsetAsync(ts_off, 0, 20000 * 4, stream);
  hipMemsetAsync(ee_off, 0, 10000 * 4, stream);
  hipMemsetAsync(st_off, 0, 50000 * 4, stream);
  hipMemsetAsync(et_off, 0, 50000 * 4, stream);
  count_k<<<1172, 256, 0, stream>>>(dst_ts, 300000, ts_off);
  count_k<<<586, 256, 0, stream>>>(dst_ee, 150000, ee_off);
  count_k<<<1172, 256, 0, stream>>>(dst_st, 300000, st_off);
  count_k<<<586, 256, 0, stream>>>(dst_et, 150000, et_off);
  scan4_k<<<4, 1024, 0, stream>>>(ts_off, 20000, ee_off, 10000, st_off, 50000, et_off, 50000);
  fill_k<<<1172, 256, 0, stream>>>(dst_ts, 300000, ts_off, ts_lst);
  fill_k<<<586, 256, 0, stream>>>(dst_ee, 150000, ee_off, ee_lst);
  fill_k<<<1172, 256, 0, stream>>>(dst_st, 300000, st_off, st_lst);
  fill_k<<<586, 256, 0, stream>>>(dst_et, 150000, et_off, et_lst);

  cumsum_p1<<<782, 256, 0, stream>>>(bert, bsum);
  cumsum_p2p<<<256, 256, 0, stream>>>(bsum, 782);
  cumsum_p3<<<782, 256, 0, stream>>>(bert, bsum, Pm);
  make_B2<<<256, 256, 0, stream>>>(Watt, Wc, B2);
  make_bias2<<<1, 256, 0, stream>>>(Watt, bc, bias2);
  make_WW<<<512, 256, 0, stream>>>(Wc, B2, Wrel, WW);
  conv8<<<dim3(96, 8), 256, 0, stream>>>(
      Wn, Wn_b, 65536, Watt, Watt_b, 131072, Wrel, Wrel_b, 131072,
      Wc, Wc_b, 65536, Wih, Wih_b, 196608, Whh, Whh_b, 196608,
      WW, WW_b, 131072, B2, B2_b, 65536);

  // ---- P1: TS attention -> h_srl ------------------------------------------
  gemm_nl<0, 0, true><<<dim3(782, 1), 256, 0, stream>>>(
      feat_tok, 256, nullptr, nullptr, nullptr, nullptr, nullptr, nullptr, nullptr, 0, 0,
      Wn_b, 256, bn, uta, 512, 0, 50000, 4);
  gemm_nl<0, 1, true><<<dim3(782, 1), 256, 0, stream>>>(
      uta, 512, nullptr, nullptr, nullptr, nullptr, nullptr, nullptr, nullptr, 0, 0,
      Watt_b, 512, nullptr, uta, 512, 256, 50000, 4);
  gemm_nl<0, 0, true><<<dim3(313, 2), 256, 0, stream>>>(
      feat_srl, 256, nullptr, nullptr, nullptr, nullptr, nullptr, nullptr, nullptr, 0, 0,
      Wn_b, 256, bn, p_srl, 256, 0, 20000, 2);
  gemm_nl<0, 1, true><<<dim3(313, 2), 256, 0, stream>>>(
      p_srl, 256, nullptr, nullptr, nullptr, nullptr, nullptr, nullptr, nullptr, 0, 0,
      Watt_b + 256, 512, batt, a_dst, 256, 0, 20000, 2);
  agg_ts2<<<20000, 256, 0, stream>>>(ts_off, ts_lst, src_ts, uta, a_dst, out_hsrl);

  // ---- P2: EE attention -> h_ent ------------------------------------------
  gemm_nl<0, 0, true><<<dim3(157, 2), 256, 0, stream>>>(
      feat_ent, 256, nullptr, nullptr, nullptr, nullptr, nullptr, nullptr, nullptr, 0, 0,
      Wrel_b, 512, brel, s_ent, 256, 0, 10000, 2);
  gemm_nl<0, 0, true><<<dim3(157, 2), 256, 0, stream>>>(
      feat_ent, 256, nullptr, nullptr, nullptr, nullptr, nullptr, nullptr, nullptr, 0, 0,
      Wn_b, 256, bn, p_ent, 256, 0, 10000, 2);
  gemm_nl<0, 1, true><<<dim3(157, 2), 256, 0, stream>>>(
      s_ent, 256, nullptr, nullptr, nullptr, nullptr, nullptr, nullptr, nullptr, 0, 0,
      Wc_b, 256, bc, s2tab, 512, 0, 10000, 2);
  gemm_nl<0, 1, true><<<dim3(157, 2), 256, 0, stream>>>(
      s_ent, 256, nullptr, nullptr, nullptr, nullptr, nullptr, nullptr, nullptr, 0, 0,
      B2_b, 256, bias2, s2tab, 512, 256, 10000, 2);
  gemm_nl<0, 1, true><<<dim3(157, 2), 256, 0, stream>>>(
      p_ent, 256, nullptr, nullptr, nullptr, nullptr, nullptr, nullptr, nullptr, 0, 0,
      Watt_b + 256, 512, batt, adp, 256, 0, 10000, 2);
  for (int c = 0; c < 4; c++) {  // 2500 dsts x exactly 15 edges = 37500
    gemm_nl<2, 0, true><<<dim3(625, 1), 256, 0, stream>>>(
        nullptr, 256, Pm, span, rel_type, ee_lst, ee_off, src_ee, s2tab, c * 2500, 2500,
        WW_b, 256, nullptr, meeatt, 512, 0, 40000, 8);
    agg_ee2<<<2500, 256, 0, stream>>>(ee_off, meeatt, adp, out_hent, c * 2500);
  }

  // ---- P3: GRU gate tables + edge GRU aggregations ------------------------
  gemm_nl<0, 0, true><<<dim3(313, 3), 256, 0, stream>>>(
      out_hsrl, 256, nullptr, nullptr, nullptr, nullptr, nullptr, nullptr, nullptr, 0, 0,
      Wih_b, 256, bih, gi_srl, 768, 0, 20000, 4);
  gemm_nl<0, 0, true><<<dim3(157, 3), 256, 0, stream>>>(
      out_hent, 256, nullptr, nullptr, nullptr, nullptr, nullptr, nullptr, nullptr, 0, 0,
      Wih_b, 256, bih, gi_ent, 768, 0, 10000, 4);
  for (int c = 0; c < 2; c++) {  // gh chunks of 25000 tokens
    int base = c * 25000;
    gemm_nl<0, 0, true><<<dim3(391, 3), 256, 0, stream>>>(
        feat_tok + (size_t)base * 256, 256, nullptr, nullptr, nullptr, nullptr,
        nullptr, nullptr, nullptr, 0, 0, Whh_b, 256, bhh, ghc, 768, 0, 25000, 4);
    agg_gru2<<<25000, 256, 0, stream>>>(st_off, st_lst, src_st, gi_srl, ghc, feat_tok, hst, base);
    agg_gru2<<<25000, 256, 0, stream>>>(et_off, et_lst, src_et, gi_ent, ghc, feat_tok, het, base);
  }

  // ---- P4: h1 = GRU(x=h_ent_tok, h=h_srl_tok), 4 x 12500 rows -------------
  for (int c = 0; c < 4; c++) {
    int base = c * 12500;
    gemm_nl<0, 1, false><<<dim3(196, 3), 256, 0, stream>>>(
        het + (size_t)base * 256, 256, nullptr, nullptr, nullptr, nullptr,
        nullptr, nullptr, nullptr, 0, 0, Wih_b, 256, bih, giA, 768, 0, 12500, 4);
    gemm_nl<0, 1, false><<<dim3(196, 3), 256, 0, stream>>>(
        hst + (size_t)base * 256, 256, nullptr, nullptr, nullptr, nullptr,
        nullptr, nullptr, nullptr, 0, 0, Whh_b, 256, bhh, ghA, 768, 0, 12500, 4);
    gru_combine2<true><<<3125, 256, 0, stream>>>(giA, ghA, hst, h1, base);
  }
  // ---- P5: h_tok = GRU(x=feat_tok, h=h1) ----------------------------------
  for (int c = 0; c < 4; c++) {
    int base = c * 12500;
    gemm_nl<0, 0, false><<<dim3(196, 3), 256, 0, stream>>>(
        feat_tok + (size_t)base * 256, 256, nullptr, nullptr, nullptr, nullptr,
        nullptr, nullptr, nullptr, 0, 0, Wih_b, 256, bih, giA, 768, 0, 12500, 4);
    gemm_nl<0, 1, false><<<dim3(196, 3), 256, 0, stream>>>(
        h1 + (size_t)base * 256, 256, nullptr, nullptr, nullptr, nullptr,
        nullptr, nullptr, nullptr, 0, 0, Whh_b, 256, bhh, ghA, 768, 0, 12500, 4);
    gru_combine2<false><<<3125, 256, 0, stream>>>(giA, ghA, h1, out_htok, base);
  }
}